// Round 7
// baseline (306.327 us; speedup 1.0000x reference)
//
#include <hip/hip_runtime.h>

// 3x3 conv, stride 1, pad 1, NCHW/OIHW fp32. N=16, C=32, OC=32, H=W=256.
//
// R10: persistent 4-tile blocks + lgkm-only raw barriers + continuous load
// issue. R9 ablation: V_noread + V_nostore ~= 50us combined vs 83.7 full ->
// super-additive -> neither stream is at a wall; the kernel loses time to
// load-issue duty cycle + vmcnt(0)-drained barrier convoys. Fix, with
// traffic byte-identical to R5 (R6's inflation lesson):
//  - 512 persistent blocks (2/CU), each owns an 8-row strip = 4 h-pair
//    tiles; weights + prologue amortized 4x.
//  - ALL barriers are `s_waitcnt lgkmcnt(0)` + raw s_barrier: in-flight
//    global loads cross barriers freely; NT-store acks are never waited.
//  - schedule issues a 24-load burst in EVERY inter-barrier segment:
//    half1(t) flies across {bar, mfma0, bar}; half0(t+1) across
//    {mfma1, epilogue, bar}; half1(t+1) issued right after the h0 write.
//  - single 41KB X buffer (R5 layout XSTR=20, conflict-free verified),
//    scatter NT epilogue (R8: layout/policy exonerated, fewest barriers).

constexpr int N_  = 16;
constexpr int C_  = 32;
constexpr int OC_ = 32;
constexpr int H_  = 256;
constexpr int W_  = 256;

constexpr int TILES = 4;             // h-pair tiles per block (8 rows)
constexpr int XSTR = 20;             // ushorts per wi: 32B data (16 ic) + 8B pad
constexpr int XROW = 258 * XSTR;     // ushorts per staged row (wi = w+1)
constexpr int WSTRD = 36;            // ushorts per (t9,oc): 64B data + 8B pad
constexpr int WELEMS = 9 * 32 * WSTRD;   // 10368 ushorts
constexpr int WBYTES = WELEMS * 2;       // 20736 B (= 1296 x 16B exactly)

typedef __attribute__((ext_vector_type(4)))  short short4v;
typedef __attribute__((ext_vector_type(8)))  short short8v;
typedef __attribute__((ext_vector_type(16))) float float16v;

static __device__ __forceinline__ unsigned short f2bf(float f) {
    unsigned int u = __float_as_uint(f);
    unsigned int r = (u + 0x7FFFu + ((u >> 16) & 1u)) >> 16;   // RNE
    return (unsigned short)r;
}

// one instruction: dst.lo16 = bf16(lo), dst.hi16 = bf16(hi)
static __device__ __forceinline__ unsigned cvtpk(float lo, float hi) {
    unsigned r;
    asm("v_cvt_pk_bf16_f32 %0, %1, %2" : "=v"(r) : "v"(lo), "v"(hi));
    return r;
}

static __device__ __forceinline__ short8v load8(const unsigned short* p) {
    // 8B-aligned: two ds_read_b64
    short4v lo = *(const short4v*)p;
    short4v hi = *(const short4v*)(p + 4);
    return __builtin_shufflevector(lo, hi, 0, 1, 2, 3, 4, 5, 6, 7);
}

// lgkm-only barrier: ds ops drained + wave sync; global loads/stores in
// flight are NOT drained (the whole point). asm "memory" clobber = compiler
// fence both sides; sched_barrier pins the scheduler too (rule #18).
static __device__ __forceinline__ void bar_lgkm() {
    asm volatile("s_waitcnt lgkmcnt(0)" ::: "memory");
    __builtin_amdgcn_s_barrier();
    __builtin_amdgcn_sched_barrier(0);
}

// ---- prep: swizzled bf16 weight image, computed once per launch ----
__global__ void conv_w_prep(const float* __restrict__ wgt,
                            unsigned short* __restrict__ wp) {
    const int i = blockIdx.x * 256 + threadIdx.x;
    if (i >= OC_ * C_ * 9) return;
    const float v = wgt[i];
    const int oc  = i / 288;
    const int rem = i - oc * 288;
    const int ic  = rem / 9;
    const int t9  = rem - ic * 9;
    wp[(t9 * 32 + oc) * WSTRD + ic] = f2bf(v);
}

template<bool USE_WS>
__global__ __launch_bounds__(512, 4) void conv3x3_mfma_kernel(
    const float* __restrict__ x,     // [N][C][H][W]
    const float* __restrict__ wgt,   // [OC][C][3][3]
    const float* __restrict__ bias,  // [OC]
    const unsigned short* __restrict__ wpk,  // prepped weights (d_ws)
    float* __restrict__ out)         // [N][OC][H][W]
{
    __shared__ __align__(16) unsigned short ldsX[4 * XROW];   // 41,280 B
    __shared__ __align__(16) unsigned short ldsW[WELEMS];     // 20,736 B

    const int tid = threadIdx.x;

    // XCD-aware swizzle: 512 blocks, 8 XCDs x 64 consecutive strips.
    const int id = blockIdx.x;
    const int L  = (id & 7) * 64 + (id >> 3);
    const int n  = L >> 5;                // image 0..15
    const int h0 = (L & 31) * 8;          // strip base row (8 rows)

    const int lane = tid & 63;
    const int wv   = tid >> 6;       // wave 0..7
    const int rsel = wv >> 2;        // output row select (0/1)
    const int col  = lane & 31;      // A: oc; B/D: w col
    const int qd   = lane >> 5;      // k-quad select
    const int w0a  = (wv & 3) * 64;
    const int w0b  = (wv & 3) * 64 + 32;

    // staging map: thread -> (staged row r4, w-pair wlo, ic-quad icq)
    const int r4  = tid >> 7;        // staged input row 0..3
    const int t7  = tid & 127;
    const int wlo = t7 & 31;         // w-pair lane
    const int icq = t7 >> 5;         // 0..3 (handles ic-pairs icq and icq+4)
    const size_t HW = (size_t)H_ * W_;

    float2 a0[4], a1[4], b0r[4], b1r[4];     // in-flight load regs
    auto load_stage = [&](int t, int hf) {   // tile t, ic-half hf
        const int icg0 = hf * 16 + 2 * icq;
        const int icg1 = hf * 16 + 2 * (icq + 4);
        const int hy = h0 + 2 * t - 1 + r4;
        if (hy >= 0 && hy < H_) {
            const float* pA0 = x + ((size_t)(n * C_ + icg0) * H_ + hy) * W_;
            const float* pA1 = pA0 + HW;
            const float* pB0 = x + ((size_t)(n * C_ + icg1) * H_ + hy) * W_;
            const float* pB1 = pB0 + HW;
            #pragma unroll
            for (int wb = 0; wb < 4; ++wb) {
                const int w = wb * 64 + 2 * wlo;
                a0[wb]  = *(const float2*)(pA0 + w);
                a1[wb]  = *(const float2*)(pA1 + w);
                b0r[wb] = *(const float2*)(pB0 + w);
                b1r[wb] = *(const float2*)(pB1 + w);
            }
        } else {
            #pragma unroll
            for (int wb = 0; wb < 4; ++wb) {
                a0[wb] = a1[wb] = b0r[wb] = b1r[wb] = make_float2(0.f, 0.f);
            }
        }
    };
    auto write_stage = [&]() {       // regs -> ldsX (cvtpk waits vmcnt)
        unsigned short* dst = &ldsX[r4 * XROW];
        #pragma unroll
        for (int wb = 0; wb < 4; ++wb) {
            const int w = wb * 64 + 2 * wlo;
            *(unsigned*)&dst[(w + 1) * XSTR + 2 * icq]       = cvtpk(a0[wb].x,  a1[wb].x);
            *(unsigned*)&dst[(w + 2) * XSTR + 2 * icq]       = cvtpk(a0[wb].y,  a1[wb].y);
            *(unsigned*)&dst[(w + 1) * XSTR + 2 * (icq + 4)] = cvtpk(b0r[wb].x, b1r[wb].x);
            *(unsigned*)&dst[(w + 2) * XSTR + 2 * (icq + 4)] = cvtpk(b0r[wb].y, b1r[wb].y);
        }
    };

    // ---- prologue ----
    load_stage(0, 0);                // half0(t0) in flight

    if (USE_WS) {                    // weight image: linear int4 copy
        const int4* src = (const int4*)wpk;
        int4* dstW = (int4*)&ldsW[0];
        #pragma unroll
        for (int i2 = 0; i2 < 3; ++i2) {
            const int idx = tid + i2 * 512;
            if (idx < WBYTES / 16) dstW[idx] = src[idx];
        }
    } else {
        for (int i = tid; i < OC_ * C_ * 9; i += 512) {
            const float v = wgt[i];
            const int oc  = i / 288;
            const int rem = i - oc * 288;
            const int ic  = rem / 9;
            const int t9  = rem - ic * 9;
            ldsW[(t9 * 32 + oc) * WSTRD + ic] = f2bf(v);
        }
    }

    // bias-initialized acc template (D row = oc mapping, verified in R2)
    float16v accb;
    #pragma unroll
    for (int r = 0; r < 16; ++r)
        accb[r] = bias[(r & 3) + 8 * (r >> 2) + 4 * qd];

    write_stage();                   // half0(t0) -> LDS
    // halo columns wi=0 / wi=257: zero once, persists across all tiles
    if (tid < 32) {
        const int r  = tid >> 3;
        const int q  = tid & 7;
        const int wi = (q & 4) ? 257 : 0;
        const int c  = q & 3;
        *(unsigned long long*)&ldsX[r * XROW + wi * XSTR + c * 4] = 0ull;
    }
    load_stage(0, 1);                // half1(t0): flies across the barrier
    bar_lgkm();                      // X half0 + W staged

    auto mfma_half = [&](int hf, float16v& c0, float16v& c1) {
        #pragma unroll
        for (int kh = 0; kh < 3; ++kh) {
            #pragma unroll
            for (int kw = 0; kw < 3; ++kw) {
                const int t9 = kh * 3 + kw;
                const short8v av =
                    load8(&ldsW[(t9 * 32 + col) * WSTRD + hf * 16 + qd * 8]);
                const short8v bf0 =
                    load8(&ldsX[(rsel + kh) * XROW + (w0a + col + kw) * XSTR + qd * 8]);
                const short8v bf1 =
                    load8(&ldsX[(rsel + kh) * XROW + (w0b + col + kw) * XSTR + qd * 8]);
                c0 = __builtin_amdgcn_mfma_f32_32x32x16_bf16(av, bf0, c0, 0, 0, 0);
                c1 = __builtin_amdgcn_mfma_f32_32x32x16_bf16(av, bf1, c1, 0, 0, 0);
            }
        }
    };

    // ---- main loop: 4 h-pair tiles ----
    #pragma unroll
    for (int t = 0; t < TILES; ++t) {
        float16v acc0 = accb, acc1 = accb;

        mfma_half(0, acc0, acc1);    // reads half0(t); half1 loads in flight
        bar_lgkm();                  // half0 readers done
        write_stage();               // half1(t) -> LDS (vmcnt wait here)
        bar_lgkm();                  // half1 visible

        if (t < TILES - 1) load_stage(t + 1, 0);   // flies across mfma1+epi
        mfma_half(1, acc0, acc1);

        // scatter NT epilogue (R8: policy/layout exonerated; acks never waited)
        float* outp = out + (size_t)n * OC_ * HW + (size_t)(h0 + 2 * t + rsel) * W_;
        #pragma unroll
        for (int r = 0; r < 16; ++r) {
            const int oc = (r & 3) + 8 * (r >> 2) + 4 * qd;
            __builtin_nontemporal_store(acc0[r], &outp[(size_t)oc * HW + w0a + col]);
            __builtin_nontemporal_store(acc1[r], &outp[(size_t)oc * HW + w0b + col]);
        }

        if (t < TILES - 1) {
            bar_lgkm();              // half1 readers done
            write_stage();           // half0(t+1) -> LDS
            load_stage(t + 1, 1);    // half1(t+1): flies across barrier+mfma0
            bar_lgkm();              // half0 visible
        }
    }
}

extern "C" void kernel_launch(void* const* d_in, const int* in_sizes, int n_in,
                              void* d_out, int out_size, void* d_ws, size_t ws_size,
                              hipStream_t stream) {
    const float* x    = (const float*)d_in[0];
    const float* wgt  = (const float*)d_in[1];
    const float* bias = (const float*)d_in[2];
    float* out        = (float*)d_out;

    dim3 grid(N_ * H_ / (2 * TILES));   // 512 blocks: one per 8-row strip
    dim3 block(512);

    if (d_ws != nullptr && ws_size >= (size_t)WBYTES) {
        unsigned short* wp = (unsigned short*)d_ws;
        conv_w_prep<<<dim3(36), dim3(256), 0, stream>>>(wgt, wp);
        conv3x3_mfma_kernel<true><<<grid, block, 0, stream>>>(x, wgt, bias, wp, out);
    } else {
        conv3x3_mfma_kernel<false><<<grid, block, 0, stream>>>(x, wgt, bias, nullptr, out);
    }
}

// Round 10
// 242.248 us; speedup vs baseline: 1.2645x; 1.2645x over previous
//
#include <hip/hip_runtime.h>

// 3x3 conv, stride 1, pad 1, NCHW/OIHW fp32. N=16, C=32, OC=32, H=W=256.
//
// R11 (2nd resubmit; rounds 8-9 died in container acquire/push -- input
// push happens before kernel execution, and R10 ran this exact barrier
// helper to completion, so the kernel is exonerated; sched_barrier dropped
// from the helper as a compiler-side hedge).
// = R7 (byte-minimal geometry, 83.7us) x R10's free-run barriers.
//  R10 taught: lgkm-only barriers raise the mixed-traffic rate 2.4->3.0
//  TB/s, but its strip geometry + scatter-NT stores inflated bytes 2.24x.
//  Fix: keep R7's 2048 h-pair blocks (proven 65.7MB FETCH) and the
//  transposed epilogue (full 1KB-line stores -- amplification-proof at any
//  timing), change ONLY the barriers: s_waitcnt lgkmcnt(0) + s_barrier.
//  Global loads cross barriers freely (reg-dependence enforces vmcnt at
//  cvtpk); all LDS hazards are ds-ops covered by lgkmcnt; nobody reads out.
//  Single variable vs R7's measured 83.7us.

constexpr int N_  = 16;
constexpr int C_  = 32;
constexpr int OC_ = 32;
constexpr int H_  = 256;
constexpr int W_  = 256;

constexpr int XSTR = 20;             // ushorts per wi: 32B data (16 ic) + 8B pad
constexpr int XROW = 258 * XSTR;     // ushorts per staged row (wi = w+1)
constexpr int WSTRD = 36;            // ushorts per (t9,oc): 64B data + 8B pad
constexpr int WELEMS = 9 * 32 * WSTRD;   // 10368 ushorts
constexpr int WBYTES = WELEMS * 2;       // 20736 B (= 1296 x 16B exactly)

typedef __attribute__((ext_vector_type(4)))  short short4v;
typedef __attribute__((ext_vector_type(8)))  short short8v;
typedef __attribute__((ext_vector_type(16))) float float16v;
typedef __attribute__((ext_vector_type(4)))  float floatx4;

static __device__ __forceinline__ unsigned short f2bf(float f) {
    unsigned int u = __float_as_uint(f);
    unsigned int r = (u + 0x7FFFu + ((u >> 16) & 1u)) >> 16;   // RNE
    return (unsigned short)r;
}

// one instruction: dst.lo16 = bf16(lo), dst.hi16 = bf16(hi)
static __device__ __forceinline__ unsigned cvtpk(float lo, float hi) {
    unsigned r;
    asm("v_cvt_pk_bf16_f32 %0, %1, %2" : "=v"(r) : "v"(lo), "v"(hi));
    return r;
}

static __device__ __forceinline__ short8v load8(const unsigned short* p) {
    // 8B-aligned: two ds_read_b64
    short4v lo = *(const short4v*)p;
    short4v hi = *(const short4v*)(p + 4);
    return __builtin_shufflevector(lo, hi, 0, 1, 2, 3, 4, 5, 6, 7);
}

// lgkm-only barrier: ds ops drained + wave sync; in-flight global loads and
// NT-store acks cross freely. "memory" clobber = compiler fence; s_barrier
// builtin is convergent. (Guide-validated pattern, ran in R10.)
static __device__ __forceinline__ void bar_lgkm() {
    asm volatile("s_waitcnt lgkmcnt(0)" ::: "memory");
    __builtin_amdgcn_s_barrier();
}

// ---- prep: swizzled bf16 weight image, computed once per launch ----
__global__ void conv_w_prep(const float* __restrict__ wgt,
                            unsigned short* __restrict__ wp) {
    const int i = blockIdx.x * 256 + threadIdx.x;
    if (i >= OC_ * C_ * 9) return;
    const float v = wgt[i];
    const int oc  = i / 288;
    const int rem = i - oc * 288;
    const int ic  = rem / 9;
    const int t9  = rem - ic * 9;
    wp[(t9 * 32 + oc) * WSTRD + ic] = f2bf(v);
}

template<bool USE_WS>
__global__ __launch_bounds__(512, 4) void conv3x3_mfma_kernel(
    const float* __restrict__ x,     // [N][C][H][W]
    const float* __restrict__ wgt,   // [OC][C][3][3]
    const float* __restrict__ bias,  // [OC]
    const unsigned short* __restrict__ wpk,  // prepped weights (d_ws)
    float* __restrict__ out)         // [N][OC][H][W]
{
    __shared__ __align__(16) unsigned short ldsX[4 * XROW];   // 41,280 B
    __shared__ __align__(16) unsigned short ldsW[WELEMS];     // 20,736 B

    const int tid = threadIdx.x;

    // XCD-aware swizzle: 2048 blocks, 8 XCDs x 256 consecutive (n, h-pair).
    const int id = blockIdx.x;
    const int L  = (id & 7) * 256 + (id >> 3);
    const int n  = L >> 7;           // image 0..15
    const int h  = (L & 127) * 2;    // output rows h, h+1

    const int lane = tid & 63;
    const int wv   = tid >> 6;       // wave 0..7
    const int rsel = wv >> 2;        // output row select (0/1)
    const int col  = lane & 31;      // A: oc; B/D: w col
    const int qd   = lane >> 5;      // k-quad select
    const int w0a  = (wv & 3) * 64;
    const int w0b  = (wv & 3) * 64 + 32;

    // staging map: thread -> (staged row r4, w-pair wlo, ic-quad icq)
    const int r4  = tid >> 7;        // staged input row 0..3 (= h-1+r4)
    const int t7  = tid & 127;
    const int wlo = t7 & 31;         // w-pair lane
    const int icq = t7 >> 5;         // 0..3 (handles ic-pairs icq and icq+4)
    const size_t HW = (size_t)H_ * W_;

    // ---- issue half0 x loads first (earliest possible) ----
    float2 a0[4], a1[4], b0r[4], b1r[4];
    auto load_half = [&](int half) {
        const int icg0 = half * 16 + 2 * icq;
        const int icg1 = half * 16 + 2 * (icq + 4);
        const int hy = h - 1 + r4;
        if (hy >= 0 && hy < H_) {
            const float* pA0 = x + ((size_t)(n * C_ + icg0) * H_ + hy) * W_;
            const float* pA1 = pA0 + HW;
            const float* pB0 = x + ((size_t)(n * C_ + icg1) * H_ + hy) * W_;
            const float* pB1 = pB0 + HW;
            #pragma unroll
            for (int wb = 0; wb < 4; ++wb) {
                const int w = wb * 64 + 2 * wlo;
                a0[wb]  = *(const float2*)(pA0 + w);
                a1[wb]  = *(const float2*)(pA1 + w);
                b0r[wb] = *(const float2*)(pB0 + w);
                b1r[wb] = *(const float2*)(pB1 + w);
            }
        } else {
            #pragma unroll
            for (int wb = 0; wb < 4; ++wb) {
                a0[wb] = a1[wb] = b0r[wb] = b1r[wb] = make_float2(0.f, 0.f);
            }
        }
    };
    load_half(0);

    // ---- weight stage ----
    if (USE_WS) {
        const int4* src = (const int4*)wpk;
        int4* dstW = (int4*)&ldsW[0];
        #pragma unroll
        for (int i2 = 0; i2 < 3; ++i2) {
            const int idx = tid + i2 * 512;
            if (idx < WBYTES / 16) dstW[idx] = src[idx];
        }
    } else {
        for (int i = tid; i < OC_ * C_ * 9; i += 512) {
            const float v = wgt[i];
            const int oc  = i / 288;
            const int rem = i - oc * 288;
            const int ic  = rem / 9;
            const int t9  = rem - ic * 9;
            ldsW[(t9 * 32 + oc) * WSTRD + ic] = f2bf(v);
        }
    }

    // ---- acc init with bias (D row = oc mapping, verified in R2) ----
    float16v acc0, acc1;
    #pragma unroll
    for (int r = 0; r < 16; ++r) {
        const float bv = bias[(r & 3) + 8 * (r >> 2) + 4 * qd];
        acc0[r] = bv;
        acc1[r] = bv;
    }

    auto write_half = [&]() {
        unsigned short* dst = &ldsX[r4 * XROW];
        #pragma unroll
        for (int wb = 0; wb < 4; ++wb) {
            const int w = wb * 64 + 2 * wlo;
            *(unsigned*)&dst[(w + 1) * XSTR + 2 * icq]       = cvtpk(a0[wb].x,  a1[wb].x);
            *(unsigned*)&dst[(w + 2) * XSTR + 2 * icq]       = cvtpk(a0[wb].y,  a1[wb].y);
            *(unsigned*)&dst[(w + 1) * XSTR + 2 * (icq + 4)] = cvtpk(b0r[wb].x, b1r[wb].x);
            *(unsigned*)&dst[(w + 2) * XSTR + 2 * (icq + 4)] = cvtpk(b0r[wb].y, b1r[wb].y);
        }
    };

    auto mfma_half = [&](int half) {
        #pragma unroll
        for (int kh = 0; kh < 3; ++kh) {
            #pragma unroll
            for (int kw = 0; kw < 3; ++kw) {
                const int t9 = kh * 3 + kw;
                const short8v av =
                    load8(&ldsW[(t9 * 32 + col) * WSTRD + half * 16 + qd * 8]);
                const short8v bf0 =
                    load8(&ldsX[(rsel + kh) * XROW + (w0a + col + kw) * XSTR + qd * 8]);
                const short8v bf1 =
                    load8(&ldsX[(rsel + kh) * XROW + (w0b + col + kw) * XSTR + qd * 8]);
                acc0 = __builtin_amdgcn_mfma_f32_32x32x16_bf16(av, bf0, acc0, 0, 0, 0);
                acc1 = __builtin_amdgcn_mfma_f32_32x32x16_bf16(av, bf1, acc1, 0, 0, 0);
            }
        }
    };

    // ---- pack + write half0; halo zeros (persist across both halves) ----
    write_half();
    if (tid < 32) {
        const int r  = tid >> 3;                 // staged row 0..3
        const int q  = tid & 7;
        const int wi = (q & 4) ? 257 : 0;
        const int c  = q & 3;
        *(unsigned long long*)&ldsX[r * XROW + wi * XSTR + c * 4] = 0ull;
    }
    bar_lgkm();                      // X0 + W staged (loads cross freely)

    // half1 loads fly across mfma0; cvtpk's reg-dependence waits vmcnt
    load_half(1);
    mfma_half(0);
    bar_lgkm();                      // MFMA0 ds reads done

    write_half();
    bar_lgkm();                      // X1 staged
    mfma_half(1);

    // ---- epilogue: LDS transpose -> full 1KB-per-instr NT row stores ----
    bar_lgkm();                      // all frag reads of ldsX done
    float* scr = (float*)&ldsX[0];   // 32 KB scratch: [32 oc][256 w]
    #pragma unroll
    for (int rr = 0; rr < 2; ++rr) {
        if (rsel == rr) {            // wave-uniform branch
            #pragma unroll
            for (int r = 0; r < 16; ++r) {
                const int oc = (r & 3) + 8 * (r >> 2) + 4 * qd;
                scr[oc * 256 + w0a + col] = acc0[r];
                scr[oc * 256 + w0b + col] = acc1[r];
            }
        }
        bar_lgkm();                  // scratch visible
        float* outp = out + (size_t)n * OC_ * HW + (size_t)(h + rr) * W_;
        #pragma unroll
        for (int k = 0; k < 4; ++k) {
            const int oc = wv * 4 + k;
            const floatx4 v = *(const floatx4*)&scr[oc * 256 + lane * 4];
            floatx4* dp = (floatx4*)(outp + (size_t)oc * HW + lane * 4);
            __builtin_nontemporal_store(v, dp);
        }
        if (rr == 0) bar_lgkm();     // row0 scr reads done before row1 dump
    }
}

extern "C" void kernel_launch(void* const* d_in, const int* in_sizes, int n_in,
                              void* d_out, int out_size, void* d_ws, size_t ws_size,
                              hipStream_t stream) {
    const float* x    = (const float*)d_in[0];
    const float* wgt  = (const float*)d_in[1];
    const float* bias = (const float*)d_in[2];
    float* out        = (float*)d_out;

    dim3 grid(N_ * H_ / 2);   // 2048 blocks: one per (n, h-pair)
    dim3 block(512);

    if (d_ws != nullptr && ws_size >= (size_t)WBYTES) {
        unsigned short* wp = (unsigned short*)d_ws;
        conv_w_prep<<<dim3(36), dim3(256), 0, stream>>>(wgt, wp);
        conv3x3_mfma_kernel<true><<<grid, block, 0, stream>>>(x, wgt, bias, wp, out);
    } else {
        conv3x3_mfma_kernel<false><<<grid, block, 0, stream>>>(x, wgt, bias, nullptr, out);
    }
}